// Round 1
// baseline (287.705 us; speedup 1.0000x reference)
//
#include <hip/hip_runtime.h>

#define TT 4096
#define DIN 1024

typedef _Float16 f16;
typedef __attribute__((ext_vector_type(8))) _Float16 f16x8;
typedef __attribute__((ext_vector_type(4))) float f32x4;

// ---- device-global scratch (static allocation; graph-capture safe) ----
__device__ f16 g_xh[TT * DIN];               // x cast to f16            8 MB
__device__ f16 g_wqkvT[3 * DIN * DIN];       // [Wq^T|Wk^T|Wv^T] f16     6 MB
__device__ f16 g_wrT[DIN * DIN];             // Wr^T f16                 2 MB
__device__ f16 g_q[TT * DIN];                // q                        8 MB
__device__ f16 g_k[TT * DIN];                // k                        8 MB
__device__ f16 g_vT[DIN * TT];               // v transposed             8 MB
__device__ f16 g_sg[(size_t)TT * TT];        // gamma .* (q k^T)        32 MB
__device__ f16 g_ret[TT * DIN];              // retained                 8 MB

// ---- prep kernels ----
__global__ void prep_cast_x(const float* __restrict__ x) {
    int i = blockIdx.x * 256 + threadIdx.x;
    g_xh[i] = (f16)x[i];
}

// output-coalesced transpose-cast: dst[j*1024+k] = src[k*1024+j]
__global__ void prep_transpose(const float* __restrict__ Wq, const float* __restrict__ Wk,
                               const float* __restrict__ Wv, const float* __restrict__ Wr) {
    int idx = blockIdx.x * 256 + threadIdx.x;       // 0 .. 1M-1
    int which = blockIdx.y;                          // 0..3
    const float* src = (which == 0) ? Wq : (which == 1) ? Wk : (which == 2) ? Wv : Wr;
    f16* dst = (which < 3) ? (g_wqkvT + (size_t)which * DIN * DIN) : g_wrT;
    int j = idx >> 10, k = idx & 1023;
    dst[idx] = (f16)src[k * DIN + j];
}

// ---- async global->LDS, 16B per lane, wave-uniform LDS base ----
__device__ __forceinline__ void gload_lds16(const f16* g, f16* l) {
    __builtin_amdgcn_global_load_lds(
        (const __attribute__((address_space(1))) unsigned int*)g,
        (__attribute__((address_space(3))) unsigned int*)l,
        16, 0, 0);
}

// ---- GEMM C = A * B^T (B stored [N][K]) with per-EPI epilogue ----
// EPI 0: A=g_xh  B=g_wqkvT K=1024 N=3072 -> q,k (row-major), v (transposed), +bias
// EPI 1: A=g_q   B=g_k     K=1024 N=4096 -> g_sg = gamma .* C
// EPI 2: A=g_sg  B=g_vT    K=4096 N=1024 -> g_ret
// EPI 3: A=g_ret B=g_wrT   K=1024 N=1024 -> out = prelu(C + br)
template <int EPI>
__global__ __launch_bounds__(256) void gemm_bt(const float* __restrict__ gamma,
                                               const float* __restrict__ bq,
                                               const float* __restrict__ bk,
                                               const float* __restrict__ bv,
                                               const float* __restrict__ br,
                                               const float* __restrict__ prelu_a,
                                               float* __restrict__ out) {
    constexpr int K   = (EPI == 2) ? 4096 : 1024;
    constexpr int ldA = (EPI == 2) ? 4096 : 1024;
    constexpr int ldB = (EPI == 2) ? 4096 : 1024;

    const f16* A = (EPI == 0) ? g_xh : (EPI == 1) ? g_q : (EPI == 2) ? g_sg : g_ret;
    const f16* B = (EPI == 0) ? g_wqkvT : (EPI == 1) ? g_k : (EPI == 2) ? g_vT : g_wrT;

    __shared__ f16 As[128 * 32];
    __shared__ f16 Bs[128 * 32];

    const int t = threadIdx.x;
    const int w = t >> 6, l = t & 63;
    const int wr = w >> 1, wc = w & 1;
    const int brow = blockIdx.y, bcol = blockIdx.x;

    const int sr = l >> 2;            // staging row within 16-row group
    const int sc = (l & 3) * 8;       // staging col (halves)
    const int arow0 = brow * 128;
    const int bcol0 = bcol * 128;

    const int fr = l & 15;            // fragment row
    const int fk = (l >> 4) * 8;      // fragment k offset (halves)

    f32x4 acc[4][4] = {};

    for (int k0 = 0; k0 < K; k0 += 32) {
#pragma unroll
        for (int c = 0; c < 2; ++c) {
            int g = w * 2 + c;
            gload_lds16(&A[(size_t)(arow0 + g * 16 + sr) * ldA + k0 + sc], &As[g * 512]);
            gload_lds16(&B[(size_t)(bcol0 + g * 16 + sr) * ldB + k0 + sc], &Bs[g * 512]);
        }
        __syncthreads();

        f16x8 af[4], bf[4];
#pragma unroll
        for (int m = 0; m < 4; ++m)
            af[m] = *(const f16x8*)&As[(wr * 64 + m * 16 + fr) * 32 + fk];
#pragma unroll
        for (int n = 0; n < 4; ++n)
            bf[n] = *(const f16x8*)&Bs[(wc * 64 + n * 16 + fr) * 32 + fk];
#pragma unroll
        for (int m = 0; m < 4; ++m)
#pragma unroll
            for (int n = 0; n < 4; ++n)
                acc[m][n] = __builtin_amdgcn_mfma_f32_16x16x32_f16(af[m], bf[n], acc[m][n], 0, 0, 0);
        __syncthreads();
    }

    // epilogue: C/D layout col = lane&15, row = (lane>>4)*4 + j   [verified m89]
    const float pa = (EPI == 3) ? *prelu_a : 0.f;
#pragma unroll
    for (int m = 0; m < 4; ++m) {
#pragma unroll
        for (int n = 0; n < 4; ++n) {
            const int row0 = arow0 + wr * 64 + m * 16 + (l >> 4) * 4;
            const int col  = bcol0 + wc * 64 + n * 16 + (l & 15);
#pragma unroll
            for (int j = 0; j < 4; ++j) {
                const int row = row0 + j;
                float v = acc[m][n][j];
                if constexpr (EPI == 0) {
                    if (col < 1024) {
                        g_q[row * 1024 + col] = (f16)(v + bq[col]);
                    } else if (col < 2048) {
                        g_k[row * 1024 + (col - 1024)] = (f16)(v + bk[col - 1024]);
                    } else {
                        g_vT[(size_t)(col - 2048) * TT + row] = (f16)(v + bv[col - 2048]);
                    }
                } else if constexpr (EPI == 1) {
                    float g = gamma[(size_t)row * TT + col];
                    g_sg[(size_t)row * TT + col] = (f16)(v * g);
                } else if constexpr (EPI == 2) {
                    g_ret[row * 1024 + col] = (f16)v;
                } else {
                    float o = v + br[col];
                    o = (o >= 0.f) ? o : pa * o;
                    out[(size_t)row * 1024 + col] = o;
                }
            }
        }
    }
}

extern "C" void kernel_launch(void* const* d_in, const int* in_sizes, int n_in,
                              void* d_out, int out_size, void* d_ws, size_t ws_size,
                              hipStream_t stream) {
    const float* x     = (const float*)d_in[0];
    const float* gamma = (const float*)d_in[1];
    const float* Wq    = (const float*)d_in[2];
    const float* bq    = (const float*)d_in[3];
    const float* Wk    = (const float*)d_in[4];
    const float* bk    = (const float*)d_in[5];
    const float* Wv    = (const float*)d_in[6];
    const float* bv    = (const float*)d_in[7];
    const float* Wr    = (const float*)d_in[8];
    const float* br    = (const float*)d_in[9];
    const float* pa    = (const float*)d_in[10];
    float* out = (float*)d_out;

    prep_cast_x<<<TT * DIN / 256, 256, 0, stream>>>(x);
    prep_transpose<<<dim3(DIN * DIN / 256, 4), 256, 0, stream>>>(Wq, Wk, Wv, Wr);

    // EPI 0: qkv  M=4096 N=3072
    gemm_bt<0><<<dim3(24, 32), 256, 0, stream>>>(gamma, bq, bk, bv, br, pa, out);
    // EPI 1: scores*gamma  M=4096 N=4096
    gemm_bt<1><<<dim3(32, 32), 256, 0, stream>>>(gamma, bq, bk, bv, br, pa, out);
    // EPI 2: retained  M=4096 N=1024
    gemm_bt<2><<<dim3(8, 32), 256, 0, stream>>>(gamma, bq, bk, bv, br, pa, out);
    // EPI 3: out  M=4096 N=1024
    gemm_bt<3><<<dim3(8, 32), 256, 0, stream>>>(gamma, bq, bk, bv, br, pa, out);
}

// Round 2
// 281.527 us; speedup vs baseline: 1.0219x; 1.0219x over previous
//
#include <hip/hip_runtime.h>

#define TT 4096
#define DIN 1024

typedef _Float16 f16;
typedef __attribute__((ext_vector_type(8))) _Float16 f16x8;
typedef __attribute__((ext_vector_type(4))) _Float16 f16x4;
typedef __attribute__((ext_vector_type(4))) float f32x4;

// ---- device-global scratch ----
__device__ f16 g_xh[TT * DIN];               // x cast to f16            8 MB
__device__ f16 g_wqkvT[3 * DIN * DIN];       // [Wq^T|Wk^T|Wv^T] f16     6 MB
__device__ f16 g_wrT[DIN * DIN];             // Wr^T f16                 2 MB
__device__ f16 g_q[TT * DIN];                // q                        8 MB
__device__ f16 g_k[TT * DIN];                // k                        8 MB
__device__ f16 g_v[TT * DIN];                // v row-major              8 MB
__device__ f16 g_vT[DIN * TT];               // v transposed             8 MB
__device__ f16 g_sg[(size_t)TT * TT];        // gamma .* (q k^T)        32 MB
__device__ float g_part[4][TT * DIN];        // split-K partials        64 MB
__device__ f16 g_ret[TT * DIN];              // retained                 8 MB

// ---- prep kernels ----
__global__ void prep_cast_x(const float* __restrict__ x) {
    int i = blockIdx.x * 256 + threadIdx.x;
    g_xh[i] = (f16)x[i];
}

__global__ void prep_transpose(const float* __restrict__ Wq, const float* __restrict__ Wk,
                               const float* __restrict__ Wv, const float* __restrict__ Wr) {
    int idx = blockIdx.x * 256 + threadIdx.x;       // 0 .. 1M-1
    int which = blockIdx.y;                          // 0..3
    const float* src = (which == 0) ? Wq : (which == 1) ? Wk : (which == 2) ? Wv : Wr;
    f16* dst = (which < 3) ? (g_wqkvT + (size_t)which * DIN * DIN) : g_wrT;
    int j = idx >> 10, k = idx & 1023;
    dst[idx] = (f16)src[k * DIN + j];
}

// LDS-tiled transpose: g_v [4096][1024] -> g_vT [1024][4096]
__global__ __launch_bounds__(256) void transpose_v() {
    __shared__ f16 t[64][72];                        // 72 keeps rows 16B-aligned
    const int bc = blockIdx.x;                       // INTER / 64
    const int br = blockIdx.y;                       // T / 64
    const int tdx = threadIdx.x;
    const int r0 = tdx >> 3;                         // 0..31
    const int c8 = (tdx & 7) * 8;                    // 0..56
#pragma unroll
    for (int p = 0; p < 2; ++p) {
        int r = r0 + p * 32;
        *(f16x8*)&t[r][c8] = *(const f16x8*)&g_v[(size_t)(br * 64 + r) * DIN + bc * 64 + c8];
    }
    __syncthreads();
#pragma unroll
    for (int p = 0; p < 2; ++p) {
        int c = r0 + p * 32;                         // output row = INTER index
        f16x8 v;
#pragma unroll
        for (int j = 0; j < 8; ++j) v[j] = t[c8 + j][c];
        *(f16x8*)&g_vT[(size_t)(bc * 64 + c) * TT + br * 64 + c8] = v;
    }
}

// ---- async global->LDS, 16B per lane ----
__device__ __forceinline__ void gload_lds16(const f16* g, f16* l) {
    __builtin_amdgcn_global_load_lds(
        (const __attribute__((address_space(1))) unsigned int*)g,
        (__attribute__((address_space(3))) unsigned int*)l,
        16, 0, 0);
}

// ---- GEMM C = A * B^T (B stored [N][K]) ----
// EPI 0: A=g_xh  B=g_wqkvT N=3072 -> q,k,v (all row-major), +bias
// EPI 1: A=g_q   B=g_k     N=4096 -> g_sg = gamma .* C  (batched gamma loads)
// EPI 2: A=g_sg  B=g_vT    N=1024 -> g_part[z], split-K over blockIdx.z
// EPI 3: A=g_ret B=g_wrT   N=1024 -> out = prelu(C + br)
template <int EPI>
__global__ __launch_bounds__(256) void gemm_bt(const float* __restrict__ gamma,
                                               const float* __restrict__ bq,
                                               const float* __restrict__ bk,
                                               const float* __restrict__ bv,
                                               const float* __restrict__ br,
                                               const float* __restrict__ prelu_a,
                                               float* __restrict__ out) {
    constexpr int K   = 1024;                        // per-chunk K for all EPIs
    constexpr int ldA = (EPI == 2) ? 4096 : 1024;
    constexpr int ldB = (EPI == 2) ? 4096 : 1024;

    const f16* A = (EPI == 0) ? g_xh : (EPI == 1) ? g_q : (EPI == 2) ? g_sg : g_ret;
    const f16* B = (EPI == 0) ? g_wqkvT : (EPI == 1) ? g_k : (EPI == 2) ? g_vT : g_wrT;
    const int kbase = (EPI == 2) ? blockIdx.z * 1024 : 0;

    __shared__ f16 As[128 * 32];
    __shared__ f16 Bs[128 * 32];

    const int t = threadIdx.x;
    const int w = t >> 6, l = t & 63;
    const int wr = w >> 1, wc = w & 1;
    const int arow0 = blockIdx.y * 128;
    const int bcol0 = blockIdx.x * 128;

    const int sr = l >> 2;            // staging row within 16-row group
    const int sc = (l & 3) * 8;       // staging col (halves)
    const int fr = l & 15;            // fragment row
    const int fk = (l >> 4) * 8;      // fragment k offset (halves)

    f32x4 acc[4][4] = {};

    for (int k0 = 0; k0 < K; k0 += 32) {
#pragma unroll
        for (int c = 0; c < 2; ++c) {
            int g = w * 2 + c;
            gload_lds16(&A[(size_t)(arow0 + g * 16 + sr) * ldA + kbase + k0 + sc], &As[g * 512]);
            gload_lds16(&B[(size_t)(bcol0 + g * 16 + sr) * ldB + kbase + k0 + sc], &Bs[g * 512]);
        }
        __syncthreads();

        f16x8 af[4], bf[4];
#pragma unroll
        for (int m = 0; m < 4; ++m)
            af[m] = *(const f16x8*)&As[(wr * 64 + m * 16 + fr) * 32 + fk];
#pragma unroll
        for (int n = 0; n < 4; ++n)
            bf[n] = *(const f16x8*)&Bs[(wc * 64 + n * 16 + fr) * 32 + fk];
#pragma unroll
        for (int m = 0; m < 4; ++m)
#pragma unroll
            for (int n = 0; n < 4; ++n)
                acc[m][n] = __builtin_amdgcn_mfma_f32_16x16x32_f16(af[m], bf[n], acc[m][n], 0, 0, 0);
        __syncthreads();
    }

    // epilogue: C/D layout col = lane&15, row = (lane>>4)*4 + j
    const int rbase = (l >> 4) * 4;
    if constexpr (EPI == 1) {
        // batched gamma: per m-chunk, issue all 16 loads, then all uses (MLP)
#pragma unroll
        for (int m = 0; m < 4; ++m) {
            const int row0 = arow0 + wr * 64 + m * 16 + rbase;
            float gv[4][4];
#pragma unroll
            for (int n = 0; n < 4; ++n) {
                const int col = bcol0 + wc * 64 + n * 16 + (l & 15);
#pragma unroll
                for (int j = 0; j < 4; ++j)
                    gv[n][j] = gamma[(size_t)(row0 + j) * TT + col];
            }
#pragma unroll
            for (int n = 0; n < 4; ++n) {
                const int col = bcol0 + wc * 64 + n * 16 + (l & 15);
#pragma unroll
                for (int j = 0; j < 4; ++j)
                    g_sg[(size_t)(row0 + j) * TT + col] = (f16)(acc[m][n][j] * gv[n][j]);
            }
        }
    } else {
        const float pa = (EPI == 3) ? *prelu_a : 0.f;
        float* gp = (EPI == 2) ? g_part[blockIdx.z] : nullptr;
#pragma unroll
        for (int m = 0; m < 4; ++m) {
#pragma unroll
            for (int n = 0; n < 4; ++n) {
                const int row0 = arow0 + wr * 64 + m * 16 + rbase;
                const int col  = bcol0 + wc * 64 + n * 16 + (l & 15);
#pragma unroll
                for (int j = 0; j < 4; ++j) {
                    const int row = row0 + j;
                    float v = acc[m][n][j];
                    if constexpr (EPI == 0) {
                        if (col < 1024) {
                            g_q[row * 1024 + col] = (f16)(v + bq[col]);
                        } else if (col < 2048) {
                            g_k[row * 1024 + (col - 1024)] = (f16)(v + bk[col - 1024]);
                        } else {
                            g_v[row * 1024 + (col - 2048)] = (f16)(v + bv[col - 2048]);
                        }
                    } else if constexpr (EPI == 2) {
                        gp[row * 1024 + col] = v;
                    } else if constexpr (EPI == 3) {
                        float o = v + br[col];
                        o = (o >= 0.f) ? o : pa * o;
                        out[(size_t)row * 1024 + col] = o;
                    }
                }
            }
        }
    }
}

// sum 4 split-K partials, cast to f16
__global__ __launch_bounds__(256) void reduce_parts() {
    int i = blockIdx.x * 256 + threadIdx.x;          // f32x4 index, 1M total
    const f32x4* p0 = (const f32x4*)g_part[0];
    const f32x4* p1 = (const f32x4*)g_part[1];
    const f32x4* p2 = (const f32x4*)g_part[2];
    const f32x4* p3 = (const f32x4*)g_part[3];
    f32x4 s = p0[i] + p1[i] + p2[i] + p3[i];
    f16x4 o;
#pragma unroll
    for (int j = 0; j < 4; ++j) o[j] = (f16)s[j];
    *(f16x4*)&g_ret[i * 4] = o;
}

extern "C" void kernel_launch(void* const* d_in, const int* in_sizes, int n_in,
                              void* d_out, int out_size, void* d_ws, size_t ws_size,
                              hipStream_t stream) {
    const float* x     = (const float*)d_in[0];
    const float* gamma = (const float*)d_in[1];
    const float* Wq    = (const float*)d_in[2];
    const float* bq    = (const float*)d_in[3];
    const float* Wk    = (const float*)d_in[4];
    const float* bk    = (const float*)d_in[5];
    const float* Wv    = (const float*)d_in[6];
    const float* bv    = (const float*)d_in[7];
    const float* Wr    = (const float*)d_in[8];
    const float* br    = (const float*)d_in[9];
    const float* pa    = (const float*)d_in[10];
    float* out = (float*)d_out;

    prep_cast_x<<<TT * DIN / 256, 256, 0, stream>>>(x);
    prep_transpose<<<dim3(DIN * DIN / 256, 4), 256, 0, stream>>>(Wq, Wk, Wv, Wr);

    // EPI 0: qkv  M=4096 N=3072 K=1024   (768 blocks, 3/CU)
    gemm_bt<0><<<dim3(24, 32), 256, 0, stream>>>(gamma, bq, bk, bv, br, pa, out);
    transpose_v<<<dim3(16, 64), 256, 0, stream>>>();
    // EPI 1: scores*gamma  M=4096 N=4096 K=1024   (1024 blocks, 4/CU)
    gemm_bt<1><<<dim3(32, 32), 256, 0, stream>>>(gamma, bq, bk, bv, br, pa, out);
    // EPI 2: retained partials, split-K=4  (8x32x4 = 1024 blocks, 4/CU)
    gemm_bt<2><<<dim3(8, 32, 4), 256, 0, stream>>>(gamma, bq, bk, bv, br, pa, out);
    reduce_parts<<<TT * DIN / 4 / 256, 256, 0, stream>>>();
    // EPI 3: out  M=4096 N=1024 K=1024   (256 blocks)
    gemm_bt<3><<<dim3(8, 32), 256, 0, stream>>>(gamma, bq, bk, bv, br, pa, out);
}

// Round 4
// 200.558 us; speedup vs baseline: 1.4345x; 1.4037x over previous
//
#include <hip/hip_runtime.h>

#define TT 4096
#define DIN 1024

typedef _Float16 f16;
typedef __attribute__((ext_vector_type(8))) _Float16 f16x8;
typedef __attribute__((ext_vector_type(4))) float f32x4;

// ---- device-global scratch ----
__device__ f16 g_xh[TT * DIN];               // x cast to f16            8 MB
__device__ f16 g_wqkvT[3 * DIN * DIN];       // [Wq^T|Wk^T|Wv^T] f16     6 MB
__device__ f16 g_wrT[DIN * DIN];             // Wr^T f16                 2 MB
__device__ f16 g_q[TT * DIN];                // q                        8 MB
__device__ f16 g_k[TT * DIN];                // k                        8 MB
__device__ f16 g_v[TT * DIN];                // v row-major              8 MB
__device__ f16 g_vT[DIN * TT];               // v transposed             8 MB
__device__ f16 g_sg[(size_t)TT * TT];        // gamma .* (q k^T)        32 MB
__device__ f16 g_part[4][TT * DIN];          // split-K partials f16    32 MB
__device__ f16 g_ret[TT * DIN];              // retained                 8 MB

// ---- prep kernels ----
__global__ void prep_cast_x(const float* __restrict__ x) {
    int i = blockIdx.x * 256 + threadIdx.x;
    g_xh[i] = (f16)x[i];
}

__global__ void prep_transpose(const float* __restrict__ Wq, const float* __restrict__ Wk,
                               const float* __restrict__ Wv, const float* __restrict__ Wr) {
    int idx = blockIdx.x * 256 + threadIdx.x;       // 0 .. 1M-1
    int which = blockIdx.y;                          // 0..3
    const float* src = (which == 0) ? Wq : (which == 1) ? Wk : (which == 2) ? Wv : Wr;
    f16* dst = (which < 3) ? (g_wqkvT + (size_t)which * DIN * DIN) : g_wrT;
    int j = idx >> 10, k = idx & 1023;
    dst[idx] = (f16)src[k * DIN + j];
}

// LDS-tiled transpose: g_v [4096][1024] -> g_vT [1024][4096]
__global__ __launch_bounds__(256) void transpose_v() {
    __shared__ f16 t[64][72];
    const int bc = blockIdx.x;
    const int br = blockIdx.y;
    const int tdx = threadIdx.x;
    const int r0 = tdx >> 3;
    const int c8 = (tdx & 7) * 8;
#pragma unroll
    for (int p = 0; p < 2; ++p) {
        int r = r0 + p * 32;
        *(f16x8*)&t[r][c8] = *(const f16x8*)&g_v[(size_t)(br * 64 + r) * DIN + bc * 64 + c8];
    }
    __syncthreads();
#pragma unroll
    for (int p = 0; p < 2; ++p) {
        int c = r0 + p * 32;
        f16x8 v;
#pragma unroll
        for (int j = 0; j < 8; ++j) v[j] = t[c8 + j][c];
        *(f16x8*)&g_vT[(size_t)(bc * 64 + c) * TT + br * 64 + c8] = v;
    }
}

// ---- async global->LDS, 16B per lane, wave-uniform LDS base ----
__device__ __forceinline__ void gload_lds16(const void* g, void* l) {
    __builtin_amdgcn_global_load_lds(
        (const __attribute__((address_space(1))) unsigned int*)g,
        (__attribute__((address_space(3))) unsigned int*)l,
        16, 0, 0);
}

// ================= 256x256 8-phase GEMM, C = A * B^T =================
// BK=64, 8 waves (2Mx4N), per-wave 128x64 out. LDS: 2 tile-buffers x 64KB.
// Per tile-buffer: A0@0 A1@16K B0@32K B1@48K (each 16KB = 128 rows x 128B).
// Swizzle: byte ^= (row&7)<<4, applied to stage SOURCE col and ds_read col.
//
// vmcnt ledger (4 loads per staged half-pair, 2 halves per A/B tile-step):
//   steady kt: outstanding = B(kt)4 + A(kt)4 + B(kt+1)4 = 12 -> vmcnt(4)
//   last  kt=NT-1: B(NT) never staged -> only 8 outstanding; vmcnt(4) would
//   leave A(NT-1) in flight while phases read it (the round-3 race).
//   Fix: full drain vmcnt(0) on the final iteration.
template <int EPI>
__global__ __launch_bounds__(512, 2) void gemm8(const float* __restrict__ gamma,
                                                const float* __restrict__ bq,
                                                const float* __restrict__ bk,
                                                const float* __restrict__ bv,
                                                const float* __restrict__ br,
                                                const float* __restrict__ prelu_a,
                                                float* __restrict__ out) {
    constexpr int NT  = 16;                          // 16 K-tiles of 64 -> K=1024
    constexpr int ld2A = (EPI == 2) ? 8192 : 2048;   // A row bytes
    constexpr int ld2B = (EPI == 2) ? 8192 : 2048;   // B row bytes

    const f16* Ap = (EPI == 0) ? g_xh : (EPI == 1) ? g_q : (EPI == 2) ? g_sg : g_ret;
    const f16* Bp = (EPI == 0) ? g_wqkvT : (EPI == 1) ? g_k : (EPI == 2) ? g_vT : g_wrT;
    const int kb_base = (EPI == 2) ? blockIdx.z * 2048 : 0;   // byte offset of K-slice

    __shared__ __align__(16) char smem[131072];

    const int t = threadIdx.x;
    const int w = t >> 6, l = t & 63;
    const int wr = w >> 2, wc = w & 3;               // 2M x 4N waves
    const int fr = l & 15;
    const int fkb = (l >> 4) * 16;                   // fragment k-byte (0..48)
    const int arow0 = blockIdx.y * 256;
    const int bcol0 = blockIdx.x * 256;

    // stage one 16KB half-tile (2 x global_load_lds dwordx4 per thread)
    auto stage = [&](const f16* M, int ld2, int row0, int kb0, int dstoff) {
#pragma unroll
        for (int r = 0; r < 2; ++r) {
            int off = r * 8192 + w * 1024;           // wave-uniform LDS offset
            int row = (off + l * 16) >> 7;           // r*64 + w*8 + l/8
            int cb  = (l & 7) * 16;
            int scb = cb ^ ((row & 7) << 4);         // inverse-swizzle the SOURCE
            const char* src = (const char*)M + (size_t)(row0 + row) * ld2 + kb0 + scb;
            gload_lds16(src, smem + dstoff + off);
        }
    };

    auto ldsA = [&](int c, int m, int ks) -> f16x8 {
        int lr = m * 16 + fr;
        int kb = ks * 64 + fkb;
        return *(const f16x8*)(smem + c * 65536 + wr * 16384 + lr * 128 + (kb ^ ((lr & 7) << 4)));
    };
    auto ldsB = [&](int c, int n, int ks) -> f16x8 {
        int lc = (wc & 1) * 64 + n * 16 + fr;
        int kb = ks * 64 + fkb;
        return *(const f16x8*)(smem + c * 65536 + 32768 + (wc >> 1) * 16384 + lc * 128 + (kb ^ ((lc & 7) << 4)));
    };

#define KB(kt) (kb_base + (kt) * 128)

    // prologue: tile0 complete + tile1 B-halves  (12 loads/thread in flight)
    stage(Ap, ld2A, arow0,       KB(0), 0);
    stage(Ap, ld2A, arow0 + 128, KB(0), 16384);
    stage(Bp, ld2B, bcol0,       KB(0), 32768);
    stage(Bp, ld2B, bcol0 + 128, KB(0), 49152);
    stage(Bp, ld2B, bcol0,       KB(1), 65536 + 32768);
    stage(Bp, ld2B, bcol0 + 128, KB(1), 65536 + 49152);

    f32x4 acc[8][4] = {};
    f16x8 bf[4][2];

#define GPHASE(MB, STAGE_STMT)                                              \
    {                                                                       \
        f16x8 af[2][2];                                                     \
        _Pragma("unroll") for (int i = 0; i < 2; ++i)                       \
            _Pragma("unroll") for (int ks = 0; ks < 2; ++ks)                \
                af[i][ks] = ldsA(c, (MB) + i, ks);                          \
        STAGE_STMT;                                                         \
        __builtin_amdgcn_s_barrier();                                       \
        __builtin_amdgcn_s_setprio(1);                                      \
        _Pragma("unroll") for (int i = 0; i < 2; ++i)                       \
            _Pragma("unroll") for (int n = 0; n < 4; ++n)                   \
                _Pragma("unroll") for (int ks = 0; ks < 2; ++ks)            \
                    acc[(MB) + i][n] = __builtin_amdgcn_mfma_f32_16x16x32_f16( \
                        af[i][ks], bf[n][ks], acc[(MB) + i][n], 0, 0, 0);   \
        __builtin_amdgcn_s_setprio(0);                                      \
        __builtin_amdgcn_s_barrier();                                       \
    }

    for (int kt = 0; kt < NT; ++kt) {
        const int c = kt & 1;
        // counted wait (see ledger above); FULL drain on the final tile —
        // B(NT) is never staged so vmcnt(4) would leave A(NT-1) in flight.
        if (kt == NT - 1) asm volatile("s_waitcnt vmcnt(0)" ::: "memory");
        else              asm volatile("s_waitcnt vmcnt(4)" ::: "memory");
        __builtin_amdgcn_s_barrier();
        // ph1: B-frags for this tile + A m0,m1 ; prefetch A0(t+1)
#pragma unroll
        for (int n = 0; n < 4; ++n)
#pragma unroll
            for (int ks = 0; ks < 2; ++ks) bf[n][ks] = ldsB(c, n, ks);
        GPHASE(0, if (kt + 1 < NT) stage(Ap, ld2A, arow0,       KB(kt + 1), (c ^ 1) * 65536))
        GPHASE(2, if (kt + 1 < NT) stage(Ap, ld2A, arow0 + 128, KB(kt + 1), (c ^ 1) * 65536 + 16384))
        GPHASE(4, if (kt + 2 < NT) stage(Bp, ld2B, bcol0,       KB(kt + 2), c * 65536 + 32768))
        GPHASE(6, if (kt + 2 < NT) stage(Bp, ld2B, bcol0 + 128, KB(kt + 2), c * 65536 + 49152))
    }
#undef GPHASE
#undef KB

    // ---------------- epilogues ----------------
    const int rb = (l >> 4) * 4;
    const int crow0 = arow0 + wr * 128;
    const int ccol0 = bcol0 + wc * 64;

    if constexpr (EPI == 0) {
        const int sel = blockIdx.x >> 2;             // 0=q 1=k 2=v
        f16* dst = (sel == 0) ? g_q : (sel == 1) ? g_k : g_v;
        const float* bias = (sel == 0) ? bq : (sel == 1) ? bk : bv;
        const int cb0 = ccol0 - sel * 1024;
#pragma unroll
        for (int m = 0; m < 8; ++m)
#pragma unroll
            for (int n = 0; n < 4; ++n) {
                const int cl = cb0 + n * 16 + fr;
                const float bsum = bias[cl];
#pragma unroll
                for (int j = 0; j < 4; ++j)
                    dst[(size_t)(crow0 + m * 16 + rb + j) * 1024 + cl] = (f16)(acc[m][n][j] + bsum);
            }
    } else if constexpr (EPI == 1) {
        __syncthreads();                             // K-loop fully drained; LDS dead
        const float* gl = (const float*)smem;
#pragma unroll 1
        for (int h = 0; h < 2; ++h) {
            // coop-load gamma rows [arow0+h*128, +128) cols [bcol0, +256) -> 128KB LDS
#pragma unroll
            for (int rr = 0; rr < 16; ++rr) {
                const char* src = (const char*)(gamma + (size_t)(arow0 + h * 128 + rr * 8 + w) * TT + bcol0) + l * 16;
                gload_lds16(src, smem + rr * 8192 + w * 1024);
            }
            __syncthreads();                         // compiler drains vmcnt before barrier
            if (wr == h) {
#pragma unroll
                for (int m = 0; m < 8; ++m)
#pragma unroll
                    for (int n = 0; n < 4; ++n) {
                        const int lcol = wc * 64 + n * 16 + fr;
#pragma unroll
                        for (int j = 0; j < 4; ++j) {
                            const int lrow = m * 16 + rb + j;
                            const float g = gl[lrow * 256 + lcol];
                            g_sg[(size_t)(crow0 + lrow) * TT + bcol0 + lcol] = (f16)(acc[m][n][j] * g);
                        }
                    }
            }
            __syncthreads();
        }
    } else if constexpr (EPI == 2) {
        f16* gp = g_part[blockIdx.z];
#pragma unroll
        for (int m = 0; m < 8; ++m)
#pragma unroll
            for (int n = 0; n < 4; ++n) {
                const int cl = ccol0 + n * 16 + fr;
#pragma unroll
                for (int j = 0; j < 4; ++j)
                    gp[(size_t)(crow0 + m * 16 + rb + j) * 1024 + cl] = (f16)acc[m][n][j];
            }
    } else {
        const float pa = *prelu_a;
#pragma unroll
        for (int m = 0; m < 8; ++m)
#pragma unroll
            for (int n = 0; n < 4; ++n) {
                const int cl = ccol0 + n * 16 + fr;
                const float bsum = br[cl];
#pragma unroll
                for (int j = 0; j < 4; ++j) {
                    float o = acc[m][n][j] + bsum;
                    o = (o >= 0.f) ? o : pa * o;
                    out[(size_t)(crow0 + m * 16 + rb + j) * 1024 + cl] = o;
                }
            }
    }
}

// sum 4 split-K f16 partials -> f16
__global__ __launch_bounds__(256) void reduce_parts() {
    size_t i = (size_t)(blockIdx.x * 256 + threadIdx.x) * 8;
    f16x8 a = *(const f16x8*)&g_part[0][i];
    f16x8 b = *(const f16x8*)&g_part[1][i];
    f16x8 cc = *(const f16x8*)&g_part[2][i];
    f16x8 d = *(const f16x8*)&g_part[3][i];
    f16x8 o;
#pragma unroll
    for (int j = 0; j < 8; ++j)
        o[j] = (f16)((float)a[j] + (float)b[j] + (float)cc[j] + (float)d[j]);
    *(f16x8*)&g_ret[i] = o;
}

extern "C" void kernel_launch(void* const* d_in, const int* in_sizes, int n_in,
                              void* d_out, int out_size, void* d_ws, size_t ws_size,
                              hipStream_t stream) {
    const float* x     = (const float*)d_in[0];
    const float* gamma = (const float*)d_in[1];
    const float* Wq    = (const float*)d_in[2];
    const float* bq    = (const float*)d_in[3];
    const float* Wk    = (const float*)d_in[4];
    const float* bk    = (const float*)d_in[5];
    const float* Wv    = (const float*)d_in[6];
    const float* bv    = (const float*)d_in[7];
    const float* Wr    = (const float*)d_in[8];
    const float* br    = (const float*)d_in[9];
    const float* pa    = (const float*)d_in[10];
    float* out = (float*)d_out;

    prep_cast_x<<<TT * DIN / 256, 256, 0, stream>>>(x);
    prep_transpose<<<dim3(DIN * DIN / 256, 4), 256, 0, stream>>>(Wq, Wk, Wv, Wr);

    // EPI 0: qkv  M=4096 N=3072
    gemm8<0><<<dim3(12, 16), 512, 0, stream>>>(gamma, bq, bk, bv, br, pa, out);
    transpose_v<<<dim3(16, 64), 256, 0, stream>>>();
    // EPI 1: gamma .* (q k^T)  M=4096 N=4096
    gemm8<1><<<dim3(16, 16), 512, 0, stream>>>(gamma, bq, bk, bv, br, pa, out);
    // EPI 2: retained partials, split-K=4
    gemm8<2><<<dim3(4, 16, 4), 512, 0, stream>>>(gamma, bq, bk, bv, br, pa, out);
    reduce_parts<<<TT * DIN / 8 / 256, 256, 0, stream>>>();
    // EPI 3: out  M=4096 N=1024
    gemm8<3><<<dim3(4, 16), 512, 0, stream>>>(gamma, bq, bk, bv, br, pa, out);
}